// Round 1
// baseline (130.030 us; speedup 1.0000x reference)
//
#include <hip/hip_runtime.h>
#include <math.h>

// Problem constants (from reference): M=256 positives, 3M=768 negatives,
// NUM_GT=32, proto (4,128,128), maps (*,64,64), gt_masks (32,512,512).

__device__ __forceinline__ float softplusf(float x) {
    // log(1+e^x), stable: max(x,0) + log1p(exp(-|x|))
    return fmaxf(x, 0.0f) + log1pf(expf(-fabsf(x)));
}

__device__ __forceinline__ float wave_sum(float v) {
    v += __shfl_down(v, 32);
    v += __shfl_down(v, 16);
    v += __shfl_down(v, 8);
    v += __shfl_down(v, 4);
    v += __shfl_down(v, 2);
    v += __shfl_down(v, 1);
    return v;
}

// T[g*4+p] = sum_{y,x in 512^2} gt_masks[g,y,x] * proto[p, y/4, x/4]
// grid (32, 16): g = blockIdx.x, row-chunk of 32 rows = blockIdx.y. 512 blocks.
__global__ void k_tmat(const float* __restrict__ gt_masks,
                       const float* __restrict__ proto,
                       float* __restrict__ T) {
    const int g = blockIdx.x;
    const int chunk = blockIdx.y;
    const float* mask = gt_masks + (size_t)g * (512 * 512);
    float tp0 = 0.f, tp1 = 0.f, tp2 = 0.f, tp3 = 0.f;
#pragma unroll 4
    for (int i = 0; i < 16; ++i) {
        int f = threadIdx.x + (i << 8);   // 0..4095 float4s in a 32x512 slab
        int yl = f >> 7;                  // 128 float4 per row
        int k  = f & 127;
        int y  = (chunk << 5) + yl;
        float4 mv = *reinterpret_cast<const float4*>(mask + y * 512 + (k << 2));
        float s = (mv.x + mv.y) + (mv.z + mv.w);   // 4 horizontal cells share proto col k, row y/4
        int cell = ((y >> 2) << 7) + k;
        tp0 = fmaf(s, proto[cell],         tp0);
        tp1 = fmaf(s, proto[16384 + cell], tp1);
        tp2 = fmaf(s, proto[32768 + cell], tp2);
        tp3 = fmaf(s, proto[49152 + cell], tp3);
    }
    tp0 = wave_sum(tp0); tp1 = wave_sum(tp1); tp2 = wave_sum(tp2); tp3 = wave_sum(tp3);
    __shared__ float smem[4][4];
    const int wave = threadIdx.x >> 6, lane = threadIdx.x & 63;
    if (lane == 0) { smem[wave][0] = tp0; smem[wave][1] = tp1; smem[wave][2] = tp2; smem[wave][3] = tp3; }
    __syncthreads();
    if (threadIdx.x < 4) {
        float s = smem[0][threadIdx.x] + smem[1][threadIdx.x] + smem[2][threadIdx.x] + smem[3][threadIdx.x];
        atomicAdd(&T[g * 4 + threadIdx.x], s);
    }
}

// cls pos/neg + smooth-L1 loc loss. One block of 256 threads; result -> acc[0].
__global__ void k_small(const float* __restrict__ map_class,
                        const float* __restrict__ map_box,
                        const float* __restrict__ anchor_center,
                        const float* __restrict__ anchor_box,
                        const float* __restrict__ gt_boxes,
                        const int* __restrict__ pos_idx,
                        const int* __restrict__ gt_idx,
                        const int* __restrict__ neg_idx,
                        float* __restrict__ acc) {
    const int t = threadIdx.x;  // 0..255 == m
    float sum = 0.f;
    const int r = pos_idx[t * 3 + 0], h = pos_idx[t * 3 + 1], w = pos_idx[t * 3 + 2];
    const int hw = h * 64 + w;
    sum += softplusf(-map_class[r * 4096 + hw]);
    for (int j = 0; j < 3; ++j) {
        int n = t + (j << 8);
        int rn = neg_idx[n * 3 + 0], hn = neg_idx[n * 3 + 1], wn = neg_idx[n * 3 + 2];
        sum += softplusf(map_class[rn * 4096 + hn * 64 + wn]);
    }
    const float ach = anchor_center[hw];
    const float acw = anchor_center[4096 + hw];
    const float ah = anchor_box[r * 2 + 0];
    const float aw = anchor_box[r * 2 + 1];
    const int g = gt_idx[t];
    const float g0 = gt_boxes[g * 4 + 0], g1 = gt_boxes[g * 4 + 1];
    const float g2 = gt_boxes[g * 4 + 2], g3 = gt_boxes[g * 4 + 3];
    float tgt[4] = { (g0 - ach) / ah, (g1 - acw) / aw, log10f(g2 / ah), log10f(g3 / aw) };
#pragma unroll
    for (int j = 0; j < 4; ++j) {
        float d = map_box[(r * 4 + j) * 4096 + hw] - tgt[j];
        float a = fabsf(d);
        sum += (a < 1.0f) ? 0.5f * d * d : a - 0.5f;
    }
    sum = wave_sum(sum);
    __shared__ float smem[4];
    const int wave = t >> 6, lane = t & 63;
    if (lane == 0) smem[wave] = sum;
    __syncthreads();
    if (t == 0) acc[0] = smem[0] + smem[1] + smem[2] + smem[3];
}

// Per-m: 16 * sum_{hw} softplus(L_m) - dot(coef_m, T[g_m])  -> atomicAdd acc[1]
// grid 256 blocks (one per positive), 256 threads.
__global__ void k_mask(const float* __restrict__ proto,
                       const float* __restrict__ map_coef,
                       const int* __restrict__ pos_idx,
                       const int* __restrict__ gt_idx,
                       const float* __restrict__ T,
                       float* __restrict__ acc) {
    const int m = blockIdx.x;
    const int r = pos_idx[m * 3 + 0], h = pos_idx[m * 3 + 1], w = pos_idx[m * 3 + 2];
    const int off = (r << 2) * 4096 + h * 64 + w;
    const float c0 = map_coef[off];
    const float c1 = map_coef[off + 4096];
    const float c2 = map_coef[off + 8192];
    const float c3 = map_coef[off + 12288];
    float sp = 0.f;
#pragma unroll 4
    for (int i = 0; i < 16; ++i) {
        int f = (threadIdx.x + (i << 8)) << 2;   // float index, float4-aligned
        float4 p0 = *reinterpret_cast<const float4*>(proto + f);
        float4 p1 = *reinterpret_cast<const float4*>(proto + 16384 + f);
        float4 p2 = *reinterpret_cast<const float4*>(proto + 32768 + f);
        float4 p3 = *reinterpret_cast<const float4*>(proto + 49152 + f);
        float L;
        L = fmaf(c3, p3.x, fmaf(c2, p2.x, fmaf(c1, p1.x, c0 * p0.x))); sp += softplusf(L);
        L = fmaf(c3, p3.y, fmaf(c2, p2.y, fmaf(c1, p1.y, c0 * p0.y))); sp += softplusf(L);
        L = fmaf(c3, p3.z, fmaf(c2, p2.z, fmaf(c1, p1.z, c0 * p0.z))); sp += softplusf(L);
        L = fmaf(c3, p3.w, fmaf(c2, p2.w, fmaf(c1, p1.w, c0 * p0.w))); sp += softplusf(L);
    }
    sp = wave_sum(sp);
    __shared__ float smem[4];
    const int wave = threadIdx.x >> 6, lane = threadIdx.x & 63;
    if (lane == 0) smem[wave] = sp;
    __syncthreads();
    if (threadIdx.x == 0) {
        float tot = smem[0] + smem[1] + smem[2] + smem[3];
        const int g = gt_idx[m];
        float dotT = fmaf(c3, T[g * 4 + 3], fmaf(c2, T[g * 4 + 2],
                     fmaf(c1, T[g * 4 + 1], c0 * T[g * 4 + 0])));
        atomicAdd(&acc[1], 16.f * tot - dotT);
    }
}

__global__ void k_final(const float* __restrict__ acc, float* __restrict__ out) {
    // total = small_losses + mask_sum / (512*512) / M
    out[0] = acc[0] + acc[1] * (1.0f / (262144.0f * 256.0f));
}

extern "C" void kernel_launch(void* const* d_in, const int* in_sizes, int n_in,
                              void* d_out, int out_size, void* d_ws, size_t ws_size,
                              hipStream_t stream) {
    const float* proto         = (const float*)d_in[0];
    const float* map_class     = (const float*)d_in[1];
    const float* map_box       = (const float*)d_in[2];
    const float* map_coef      = (const float*)d_in[3];
    const float* anchor_center = (const float*)d_in[4];
    const float* anchor_box    = (const float*)d_in[5];
    const float* gt_boxes      = (const float*)d_in[6];
    const float* gt_masks      = (const float*)d_in[7];
    const int*   pos_idx       = (const int*)d_in[8];
    const int*   gt_idx        = (const int*)d_in[9];
    const int*   neg_idx       = (const int*)d_in[10];

    float* acc = (float*)d_ws;   // acc[0]=small losses, acc[1]=mask sum
    float* T   = acc + 2;        // 32*4 floats
    float* out = (float*)d_out;

    hipMemsetAsync(d_ws, 0, 1024, stream);   // zero acc + T (graph-capturable memset node)

    dim3 gridT(32, 16);
    k_tmat<<<gridT, 256, 0, stream>>>(gt_masks, proto, T);
    k_small<<<1, 256, 0, stream>>>(map_class, map_box, anchor_center, anchor_box,
                                   gt_boxes, pos_idx, gt_idx, neg_idx, acc);
    k_mask<<<256, 256, 0, stream>>>(proto, map_coef, pos_idx, gt_idx, T, acc);
    k_final<<<1, 1, 0, stream>>>(acc, out);
}

// Round 2
// 128.163 us; speedup vs baseline: 1.0146x; 1.0146x over previous
//
#include <hip/hip_runtime.h>
#include <math.h>

// Problem constants: M=256 positives, 3M=768 negatives, NUM_GT=32,
// proto (4,128,128), maps (*,64,64), gt_masks (32,512,512).
//
// Mask-loss restructure (verified exact in round 1):
//   mean(bce_m) = (1/512^2) * [ 16 * sum_{hw in 128^2} softplus(L_m[hw])
//                               - dot(coef_m, T[gt_m]) ]
//   T[g,p] = sum_{512^2} gt_masks[g] * proto[p, y/4, x/4]
// so gt_masks (33.5 MB) is streamed exactly once (k_tmat), and the per-m
// softplus pass touches only the 256 KB L2-resident proto.

__device__ __forceinline__ float softplusf(float x) {
    return fmaxf(x, 0.0f) + log1pf(expf(-fabsf(x)));
}

__device__ __forceinline__ float wave_sum(float v) {
    v += __shfl_down(v, 32);
    v += __shfl_down(v, 16);
    v += __shfl_down(v, 8);
    v += __shfl_down(v, 4);
    v += __shfl_down(v, 2);
    v += __shfl_down(v, 1);
    return v;
}

// Tpart[chunk*128 + g*4 + p] partial sums over a 32-row slab. No atomics, no
// zero-init needed (each block owns 4 disjoint slots). Block (0,0) also zeroes
// acc_mask + counter for the next (stream-ordered) kernel.
__global__ void k_tmat(const float* __restrict__ gt_masks,
                       const float* __restrict__ proto,
                       float* __restrict__ Tpart,
                       float* __restrict__ acc_mask,
                       int* __restrict__ counter) {
    const int g = blockIdx.x;
    const int chunk = blockIdx.y;
    if (g == 0 && chunk == 0 && threadIdx.x == 0) { *acc_mask = 0.f; *counter = 0; }
    const float* mask = gt_masks + (size_t)g * (512 * 512);
    float tp0 = 0.f, tp1 = 0.f, tp2 = 0.f, tp3 = 0.f;
#pragma unroll 4
    for (int i = 0; i < 16; ++i) {
        int f = threadIdx.x + (i << 8);   // 0..4095 float4s in a 32x512 slab
        int yl = f >> 7;                  // 128 float4 per row
        int k  = f & 127;
        int y  = (chunk << 5) + yl;
        float4 mv = *reinterpret_cast<const float4*>(mask + y * 512 + (k << 2));
        float s = (mv.x + mv.y) + (mv.z + mv.w);   // 4 horiz cells share proto[*, y/4, k]
        int cell = ((y >> 2) << 7) + k;
        tp0 = fmaf(s, proto[cell],         tp0);
        tp1 = fmaf(s, proto[16384 + cell], tp1);
        tp2 = fmaf(s, proto[32768 + cell], tp2);
        tp3 = fmaf(s, proto[49152 + cell], tp3);
    }
    tp0 = wave_sum(tp0); tp1 = wave_sum(tp1); tp2 = wave_sum(tp2); tp3 = wave_sum(tp3);
    __shared__ float smem[4][4];
    const int wave = threadIdx.x >> 6, lane = threadIdx.x & 63;
    if (lane == 0) { smem[wave][0] = tp0; smem[wave][1] = tp1; smem[wave][2] = tp2; smem[wave][3] = tp3; }
    __syncthreads();
    if (threadIdx.x < 4) {
        float s = smem[0][threadIdx.x] + smem[1][threadIdx.x] + smem[2][threadIdx.x] + smem[3][threadIdx.x];
        Tpart[chunk * 128 + g * 4 + threadIdx.x] = s;
    }
}

// 256 blocks, one per positive m. Each block: mask-loss contribution ->
// atomicAdd(acc_mask); last-finishing block (ticket pattern) computes the
// cls + loc losses and writes the final scalar.
__global__ void k_maskfinal(const float* __restrict__ proto,
                            const float* __restrict__ map_coef,
                            const float* __restrict__ map_class,
                            const float* __restrict__ map_box,
                            const float* __restrict__ anchor_center,
                            const float* __restrict__ anchor_box,
                            const float* __restrict__ gt_boxes,
                            const int* __restrict__ pos_idx,
                            const int* __restrict__ gt_idx,
                            const int* __restrict__ neg_idx,
                            const float* __restrict__ Tpart,
                            float* __restrict__ acc_mask,
                            int* __restrict__ counter,
                            float* __restrict__ out) {
    const int m = blockIdx.x;
    const int t = threadIdx.x;
    const int wave = t >> 6, lane = t & 63;
    const int r = pos_idx[m * 3 + 0], h = pos_idx[m * 3 + 1], w = pos_idx[m * 3 + 2];
    const int g = gt_idx[m];
    const int off = (r << 2) * 4096 + h * 64 + w;
    const float c0 = map_coef[off];
    const float c1 = map_coef[off + 4096];
    const float c2 = map_coef[off + 8192];
    const float c3 = map_coef[off + 12288];

    float sp = 0.f;
#pragma unroll 4
    for (int i = 0; i < 16; ++i) {
        int f = (t + (i << 8)) << 2;   // float4-aligned float index
        float4 p0 = *reinterpret_cast<const float4*>(proto + f);
        float4 p1 = *reinterpret_cast<const float4*>(proto + 16384 + f);
        float4 p2 = *reinterpret_cast<const float4*>(proto + 32768 + f);
        float4 p3 = *reinterpret_cast<const float4*>(proto + 49152 + f);
        float L;
        L = fmaf(c3, p3.x, fmaf(c2, p2.x, fmaf(c1, p1.x, c0 * p0.x))); sp += softplusf(L);
        L = fmaf(c3, p3.y, fmaf(c2, p2.y, fmaf(c1, p1.y, c0 * p0.y))); sp += softplusf(L);
        L = fmaf(c3, p3.z, fmaf(c2, p2.z, fmaf(c1, p1.z, c0 * p0.z))); sp += softplusf(L);
        L = fmaf(c3, p3.w, fmaf(c2, p2.w, fmaf(c1, p1.w, c0 * p0.w))); sp += softplusf(L);
    }
    sp = wave_sum(sp);
    __shared__ float smem[4];
    __shared__ int is_last;
    if (lane == 0) smem[wave] = sp;

    // wave 0 concurrently computes dot(coef, T[g]) from the 16x4 partials
    float dotT = 0.f;
    if (wave == 0) {
        int chunk = lane >> 2, p = lane & 3;
        float cp = (p == 0) ? c0 : (p == 1) ? c1 : (p == 2) ? c2 : c3;
        dotT = Tpart[chunk * 128 + g * 4 + p] * cp;   // lanes 0..63 cover 16 chunks x 4 p
        dotT = wave_sum(dotT);
    }
    __syncthreads();
    if (t == 0) {
        float tot = smem[0] + smem[1] + smem[2] + smem[3];
        atomicAdd(acc_mask, 16.f * tot - dotT);
        __threadfence();
        int ticket = atomicAdd(counter, 1);
        is_last = (ticket == 255);
    }
    __syncthreads();
    if (!is_last) return;

    // ---- last block: cls + loc losses (each thread t == one positive m') ----
    float sum = 0.f;
    {
        const int r2 = pos_idx[t * 3 + 0], h2 = pos_idx[t * 3 + 1], w2 = pos_idx[t * 3 + 2];
        const int hw = h2 * 64 + w2;
        sum += softplusf(-map_class[r2 * 4096 + hw]);
        for (int j = 0; j < 3; ++j) {
            int n = t + (j << 8);
            int rn = neg_idx[n * 3 + 0], hn = neg_idx[n * 3 + 1], wn = neg_idx[n * 3 + 2];
            sum += softplusf(map_class[rn * 4096 + hn * 64 + wn]);
        }
        const float ach = anchor_center[hw];
        const float acw = anchor_center[4096 + hw];
        const float ah = anchor_box[r2 * 2 + 0];
        const float aw = anchor_box[r2 * 2 + 1];
        const int g2 = gt_idx[t];
        const float g0 = gt_boxes[g2 * 4 + 0], g1 = gt_boxes[g2 * 4 + 1];
        const float gg2 = gt_boxes[g2 * 4 + 2], g3 = gt_boxes[g2 * 4 + 3];
        float tgt[4] = { (g0 - ach) / ah, (g1 - acw) / aw, log10f(gg2 / ah), log10f(g3 / aw) };
#pragma unroll
        for (int j = 0; j < 4; ++j) {
            float d = map_box[(r2 * 4 + j) * 4096 + hw] - tgt[j];
            float a = fabsf(d);
            sum += (a < 1.0f) ? 0.5f * d * d : a - 0.5f;
        }
    }
    sum = wave_sum(sum);
    __syncthreads();           // smem reuse
    if (lane == 0) smem[wave] = sum;
    __syncthreads();
    if (t == 0) {
        float small = smem[0] + smem[1] + smem[2] + smem[3];
        float mask_tot = atomicAdd(acc_mask, 0.0f);   // coherent read-back
        out[0] = small + mask_tot * (1.0f / (262144.0f * 256.0f));
    }
}

extern "C" void kernel_launch(void* const* d_in, const int* in_sizes, int n_in,
                              void* d_out, int out_size, void* d_ws, size_t ws_size,
                              hipStream_t stream) {
    const float* proto         = (const float*)d_in[0];
    const float* map_class     = (const float*)d_in[1];
    const float* map_box       = (const float*)d_in[2];
    const float* map_coef      = (const float*)d_in[3];
    const float* anchor_center = (const float*)d_in[4];
    const float* anchor_box    = (const float*)d_in[5];
    const float* gt_boxes      = (const float*)d_in[6];
    const float* gt_masks      = (const float*)d_in[7];
    const int*   pos_idx       = (const int*)d_in[8];
    const int*   gt_idx        = (const int*)d_in[9];
    const int*   neg_idx       = (const int*)d_in[10];

    float* Tpart    = (float*)d_ws;        // 16*32*4 = 2048 floats
    float* acc_mask = Tpart + 2048;        // 1 float
    int*   counter  = (int*)(acc_mask + 1);
    float* out      = (float*)d_out;

    dim3 gridT(32, 16);
    k_tmat<<<gridT, 256, 0, stream>>>(gt_masks, proto, Tpart, acc_mask, counter);
    k_maskfinal<<<256, 256, 0, stream>>>(proto, map_coef, map_class, map_box,
                                         anchor_center, anchor_box, gt_boxes,
                                         pos_idx, gt_idx, neg_idx,
                                         Tpart, acc_mask, counter, out);
}

// Round 3
// 119.554 us; speedup vs baseline: 1.0876x; 1.0720x over previous
//
#include <hip/hip_runtime.h>
#include <math.h>

// Problem: M=256 positives, 3M=768 negatives, NUM_GT=32,
// proto (4,128,128), maps (*,64,64), gt_masks (32,512,512).
//
// Mask-loss restructure (verified exact in rounds 1-2):
//   mean(bce_m) = (1/512^2) * [ 16 * sum_{hw in 128^2} softplus(L_m[hw])
//                               - dot(coef_m, T[gt_m]) ]
//   T[g,p] = sum_{512^2} gt_masks[g] * proto[p, y/4, x/4]
// gt_masks (33.5 MB) is streamed exactly once; per-m softplus touches only the
// L2-resident 256 KB proto.
//
// Single-node design: 769 blocks. [0,512): tmat slabs (HBM-bound).
// [512,768): per-m softplus (VALU-bound, overlaps tmat). 768: finalizer,
// spin-waits on magic done-flags (no zero-init needed under 0xAA poison),
// then computes dotT + cls + loc and writes the scalar. All cross-block data
// published via device-scope atomics (atomicExch / atomicAdd read-back).

#define MAGIC 0x5A17C0DE
#define INV_TOTAL (1.0f / (262144.0f * 256.0f))

__device__ __forceinline__ float softplusf(float x) {
    // native v_exp_f32 / v_log_f32; abs threshold is 40.48 so ~ulp-level
    // approximation error is irrelevant.
    return fmaxf(x, 0.0f) + __logf(1.0f + __expf(-fabsf(x)));
}

__device__ __forceinline__ float wave_sum(float v) {
    v += __shfl_down(v, 32);
    v += __shfl_down(v, 16);
    v += __shfl_down(v, 8);
    v += __shfl_down(v, 4);
    v += __shfl_down(v, 2);
    v += __shfl_down(v, 1);
    return v;
}

__global__ void __launch_bounds__(256)
k_fused(const float* __restrict__ proto,
        const float* __restrict__ map_coef,
        const float* __restrict__ map_class,
        const float* __restrict__ map_box,
        const float* __restrict__ anchor_center,
        const float* __restrict__ anchor_box,
        const float* __restrict__ gt_boxes,
        const float* __restrict__ gt_masks,
        const int* __restrict__ pos_idx,
        const int* __restrict__ gt_idx,
        const int* __restrict__ neg_idx,
        float* __restrict__ Tpart,   // [512*4] slab partials, slot = bid
        float* __restrict__ SP,      // [256] per-m softplus sums
        int* __restrict__ done,      // [768] magic flags
        float* __restrict__ out) {
    const int bid = blockIdx.x;
    const int t = threadIdx.x;
    const int wave = t >> 6, lane = t & 63;
    __shared__ float smem[4][4];
    __shared__ float sT[128];

    if (bid < 512) {
        // ---- tmat: partial T over a 32-row slab of gt_masks[g] ----
        const int g = bid >> 4, chunk = bid & 15;
        const float* mask = gt_masks + (size_t)g * (512 * 512);
        float tp0 = 0.f, tp1 = 0.f, tp2 = 0.f, tp3 = 0.f;
#pragma unroll 4
        for (int i = 0; i < 16; ++i) {
            int f = t + (i << 8);            // 0..4095 float4s in 32x512 slab
            int yl = f >> 7;                 // 128 float4 per row
            int k  = f & 127;
            int y  = (chunk << 5) + yl;
            float4 mv = *reinterpret_cast<const float4*>(mask + y * 512 + (k << 2));
            float s = (mv.x + mv.y) + (mv.z + mv.w);
            int cell = ((y >> 2) << 7) + k;
            tp0 = fmaf(s, proto[cell],         tp0);
            tp1 = fmaf(s, proto[16384 + cell], tp1);
            tp2 = fmaf(s, proto[32768 + cell], tp2);
            tp3 = fmaf(s, proto[49152 + cell], tp3);
        }
        tp0 = wave_sum(tp0); tp1 = wave_sum(tp1); tp2 = wave_sum(tp2); tp3 = wave_sum(tp3);
        if (lane == 0) { smem[wave][0] = tp0; smem[wave][1] = tp1; smem[wave][2] = tp2; smem[wave][3] = tp3; }
        __syncthreads();
        if (t == 0) {
#pragma unroll
            for (int p = 0; p < 4; ++p) {
                float s = smem[0][p] + smem[1][p] + smem[2][p] + smem[3][p];
                atomicExch(&Tpart[(bid << 2) + p], s);   // coherent publish
            }
            __threadfence();
            atomicExch(&done[bid], MAGIC);
        }
        return;
    }

    if (bid < 768) {
        // ---- per-m mask softplus (no Tpart dependency) ----
        const int m = bid - 512;
        const int r = pos_idx[m * 3 + 0], h = pos_idx[m * 3 + 1], w = pos_idx[m * 3 + 2];
        const int off = (r << 2) * 4096 + h * 64 + w;
        const float c0 = map_coef[off];
        const float c1 = map_coef[off + 4096];
        const float c2 = map_coef[off + 8192];
        const float c3 = map_coef[off + 12288];
        float sp = 0.f;
#pragma unroll 4
        for (int i = 0; i < 16; ++i) {
            int f = (t + (i << 8)) << 2;
            float4 p0 = *reinterpret_cast<const float4*>(proto + f);
            float4 p1 = *reinterpret_cast<const float4*>(proto + 16384 + f);
            float4 p2 = *reinterpret_cast<const float4*>(proto + 32768 + f);
            float4 p3 = *reinterpret_cast<const float4*>(proto + 49152 + f);
            float L;
            L = fmaf(c3, p3.x, fmaf(c2, p2.x, fmaf(c1, p1.x, c0 * p0.x))); sp += softplusf(L);
            L = fmaf(c3, p3.y, fmaf(c2, p2.y, fmaf(c1, p1.y, c0 * p0.y))); sp += softplusf(L);
            L = fmaf(c3, p3.z, fmaf(c2, p2.z, fmaf(c1, p1.z, c0 * p0.z))); sp += softplusf(L);
            L = fmaf(c3, p3.w, fmaf(c2, p2.w, fmaf(c1, p1.w, c0 * p0.w))); sp += softplusf(L);
        }
        sp = wave_sum(sp);
        if (lane == 0) smem[wave][0] = sp;
        __syncthreads();
        if (t == 0) {
            float tot = smem[0][0] + smem[1][0] + smem[2][0] + smem[3][0];
            atomicExch(&SP[m], tot);                 // coherent publish
            __threadfence();
            atomicExch(&done[bid], MAGIC);
        }
        return;
    }

    // ---- finalizer block (bid == 768): wait for all 768 workers ----
    {
        const int i0 = t * 3, i1 = i0 + 1, i2 = i0 + 2;
        bool a = false, b = false, c = false;
        while (!(a && b && c)) {
            if (!a) a = (atomicAdd(&done[i0], 0) == MAGIC);
            if (!b) b = (atomicAdd(&done[i1], 0) == MAGIC);
            if (!c) c = (atomicAdd(&done[i2], 0) == MAGIC);
            if (!(a && b && c)) __builtin_amdgcn_s_sleep(2);
        }
    }
    __syncthreads();
    __threadfence();

    // Reduce Tpart -> T[32][4] in LDS (coherent atomic read-back).
    if (t < 128) {
        const int g = t >> 2, p = t & 3;
        float s = 0.f;
#pragma unroll
        for (int chunk = 0; chunk < 16; ++chunk)
            s += atomicAdd(&Tpart[(((g << 4) + chunk) << 2) + p], 0.0f);
        sT[t] = s;
    }
    const float spm = atomicAdd(&SP[t], 0.0f);       // this thread's m = t
    __syncthreads();

    // ---- per-thread m = t: cls + loc + mask combine ----
    float contrib;
    {
        const int r = pos_idx[t * 3 + 0], h = pos_idx[t * 3 + 1], w = pos_idx[t * 3 + 2];
        const int hw = h * 64 + w;
        float sum = softplusf(-map_class[r * 4096 + hw]);
        for (int j = 0; j < 3; ++j) {
            int n = t + (j << 8);
            int rn = neg_idx[n * 3 + 0], hn = neg_idx[n * 3 + 1], wn = neg_idx[n * 3 + 2];
            sum += softplusf(map_class[rn * 4096 + hn * 64 + wn]);
        }
        const float ach = anchor_center[hw];
        const float acw = anchor_center[4096 + hw];
        const float ah = anchor_box[r * 2 + 0];
        const float aw = anchor_box[r * 2 + 1];
        const int g = gt_idx[t];
        const float g0 = gt_boxes[g * 4 + 0], g1 = gt_boxes[g * 4 + 1];
        const float g2 = gt_boxes[g * 4 + 2], g3 = gt_boxes[g * 4 + 3];
        float tgt[4] = { (g0 - ach) / ah, (g1 - acw) / aw, log10f(g2 / ah), log10f(g3 / aw) };
#pragma unroll
        for (int j = 0; j < 4; ++j) {
            float d = map_box[(r * 4 + j) * 4096 + hw] - tgt[j];
            float a = fabsf(d);
            sum += (a < 1.0f) ? 0.5f * d * d : a - 0.5f;
        }
        const int off = (r << 2) * 4096 + hw;
        const float c0 = map_coef[off];
        const float c1 = map_coef[off + 4096];
        const float c2 = map_coef[off + 8192];
        const float c3 = map_coef[off + 12288];
        const float dotT = fmaf(c3, sT[g * 4 + 3], fmaf(c2, sT[g * 4 + 2],
                           fmaf(c1, sT[g * 4 + 1], c0 * sT[g * 4 + 0])));
        contrib = sum + (16.f * spm - dotT) * INV_TOTAL;
    }
    contrib = wave_sum(contrib);
    __syncthreads();
    if (lane == 0) smem[wave][0] = contrib;
    __syncthreads();
    if (t == 0)
        out[0] = smem[0][0] + smem[1][0] + smem[2][0] + smem[3][0];
}

extern "C" void kernel_launch(void* const* d_in, const int* in_sizes, int n_in,
                              void* d_out, int out_size, void* d_ws, size_t ws_size,
                              hipStream_t stream) {
    const float* proto         = (const float*)d_in[0];
    const float* map_class     = (const float*)d_in[1];
    const float* map_box       = (const float*)d_in[2];
    const float* map_coef      = (const float*)d_in[3];
    const float* anchor_center = (const float*)d_in[4];
    const float* anchor_box    = (const float*)d_in[5];
    const float* gt_boxes      = (const float*)d_in[6];
    const float* gt_masks      = (const float*)d_in[7];
    const int*   pos_idx       = (const int*)d_in[8];
    const int*   gt_idx       = (const int*)d_in[9];
    const int*   neg_idx       = (const int*)d_in[10];

    float* Tpart = (float*)d_ws;          // 2048 floats
    float* SP    = Tpart + 2048;          // 256 floats
    int*   done  = (int*)(SP + 256);      // 768 ints
    float* out   = (float*)d_out;

    k_fused<<<769, 256, 0, stream>>>(proto, map_coef, map_class, map_box,
                                     anchor_center, anchor_box, gt_boxes, gt_masks,
                                     pos_idx, gt_idx, neg_idx,
                                     Tpart, SP, done, out);
}

// Round 4
// 103.202 us; speedup vs baseline: 1.2600x; 1.1584x over previous
//
#include <hip/hip_runtime.h>
#include <math.h>

// Problem: M=256 positives, 3M=768 negatives, NUM_GT=32,
// proto (4,128,128), maps (*,64,64), gt_masks (32,512,512).
//
// Mask-loss restructure (verified exact rounds 1-3):
//   mean(bce_m) = (1/512^2) * [ 16 * sum_{hw in 128^2} softplus(L_m[hw])
//                               - dot(coef_m, T[gt_m]) ]
//   T[g,p] = sum_{512^2} gt_masks[g] * proto[p, y/4, x/4]
//
// Round-4 structure: NO atomics, NO spin. Two dispatches:
//   k_workers (768 blocks): [0,512) tmat slab partials -> Tpart (plain store);
//                           [512,768) per-m softplus -> SP (plain store).
//   k_final   (1 block): reduce Tpart, cls+loc+combine, write scalar.
// Kernel-boundary ordering on the stream guarantees visibility.

#define INV_TOTAL (1.0f / (262144.0f * 256.0f))

__device__ __forceinline__ float softplusf(float x) {
    return fmaxf(x, 0.0f) + __logf(1.0f + __expf(-fabsf(x)));
}

__device__ __forceinline__ float wave_sum(float v) {
    v += __shfl_down(v, 32);
    v += __shfl_down(v, 16);
    v += __shfl_down(v, 8);
    v += __shfl_down(v, 4);
    v += __shfl_down(v, 2);
    v += __shfl_down(v, 1);
    return v;
}

__global__ void __launch_bounds__(256)
k_workers(const float* __restrict__ proto,
          const float* __restrict__ map_coef,
          const float* __restrict__ gt_masks,
          const int* __restrict__ pos_idx,
          float* __restrict__ Tpart,   // [512*4] slab partials, slot = bid
          float* __restrict__ SP) {    // [256] per-m softplus sums
    const int bid = blockIdx.x;
    const int t = threadIdx.x;
    const int wave = t >> 6, lane = t & 63;
    __shared__ float smem[4][4];

    if (bid < 512) {
        // ---- tmat: partial T over a 32-row slab of gt_masks[g] ----
        const int g = bid >> 4, chunk = bid & 15;
        const float* mask = gt_masks + (size_t)g * (512 * 512);
        float tp0 = 0.f, tp1 = 0.f, tp2 = 0.f, tp3 = 0.f;
#pragma unroll 4
        for (int i = 0; i < 16; ++i) {
            int f = t + (i << 8);            // 0..4095 float4s in 32x512 slab
            int yl = f >> 7;                 // 128 float4 per row
            int k  = f & 127;
            int y  = (chunk << 5) + yl;
            float4 mv = *reinterpret_cast<const float4*>(mask + y * 512 + (k << 2));
            float s = (mv.x + mv.y) + (mv.z + mv.w);
            int cell = ((y >> 2) << 7) + k;
            tp0 = fmaf(s, proto[cell],         tp0);
            tp1 = fmaf(s, proto[16384 + cell], tp1);
            tp2 = fmaf(s, proto[32768 + cell], tp2);
            tp3 = fmaf(s, proto[49152 + cell], tp3);
        }
        tp0 = wave_sum(tp0); tp1 = wave_sum(tp1); tp2 = wave_sum(tp2); tp3 = wave_sum(tp3);
        if (lane == 0) { smem[wave][0] = tp0; smem[wave][1] = tp1; smem[wave][2] = tp2; smem[wave][3] = tp3; }
        __syncthreads();
        if (t < 4)
            Tpart[(bid << 2) + t] = smem[0][t] + smem[1][t] + smem[2][t] + smem[3][t];
        return;
    }

    // ---- per-m mask softplus over L2-resident proto ----
    const int m = bid - 512;
    const int r = pos_idx[m * 3 + 0], h = pos_idx[m * 3 + 1], w = pos_idx[m * 3 + 2];
    const int off = (r << 2) * 4096 + h * 64 + w;
    const float c0 = map_coef[off];
    const float c1 = map_coef[off + 4096];
    const float c2 = map_coef[off + 8192];
    const float c3 = map_coef[off + 12288];
    float sp = 0.f;
#pragma unroll 4
    for (int i = 0; i < 16; ++i) {
        int f = (t + (i << 8)) << 2;
        float4 p0 = *reinterpret_cast<const float4*>(proto + f);
        float4 p1 = *reinterpret_cast<const float4*>(proto + 16384 + f);
        float4 p2 = *reinterpret_cast<const float4*>(proto + 32768 + f);
        float4 p3 = *reinterpret_cast<const float4*>(proto + 49152 + f);
        float L;
        L = fmaf(c3, p3.x, fmaf(c2, p2.x, fmaf(c1, p1.x, c0 * p0.x))); sp += softplusf(L);
        L = fmaf(c3, p3.y, fmaf(c2, p2.y, fmaf(c1, p1.y, c0 * p0.y))); sp += softplusf(L);
        L = fmaf(c3, p3.z, fmaf(c2, p2.z, fmaf(c1, p1.z, c0 * p0.z))); sp += softplusf(L);
        L = fmaf(c3, p3.w, fmaf(c2, p2.w, fmaf(c1, p1.w, c0 * p0.w))); sp += softplusf(L);
    }
    sp = wave_sum(sp);
    if (lane == 0) smem[wave][0] = sp;
    __syncthreads();
    if (t == 0)
        SP[m] = smem[0][0] + smem[1][0] + smem[2][0] + smem[3][0];
}

__global__ void __launch_bounds__(256)
k_final(const float* __restrict__ map_class,
        const float* __restrict__ map_box,
        const float* __restrict__ map_coef,
        const float* __restrict__ anchor_center,
        const float* __restrict__ anchor_box,
        const float* __restrict__ gt_boxes,
        const int* __restrict__ pos_idx,
        const int* __restrict__ gt_idx,
        const int* __restrict__ neg_idx,
        const float* __restrict__ Tpart,
        const float* __restrict__ SP,
        float* __restrict__ out) {
    const int t = threadIdx.x;
    const int wave = t >> 6, lane = t & 63;
    __shared__ float sT[128];
    __shared__ float smem[4];

    if (t < 128) {                       // T[g][p] = sum of 16 chunk partials
        const int g = t >> 2, p = t & 3;
        float s = 0.f;
#pragma unroll
        for (int chunk = 0; chunk < 16; ++chunk)
            s += Tpart[(((g << 4) + chunk) << 2) + p];
        sT[t] = s;
    }
    __syncthreads();

    // per-thread m = t: cls + loc + mask combine
    float contrib;
    {
        const int r = pos_idx[t * 3 + 0], h = pos_idx[t * 3 + 1], w = pos_idx[t * 3 + 2];
        const int hw = h * 64 + w;
        float sum = softplusf(-map_class[r * 4096 + hw]);
        for (int j = 0; j < 3; ++j) {
            int n = t + (j << 8);
            int rn = neg_idx[n * 3 + 0], hn = neg_idx[n * 3 + 1], wn = neg_idx[n * 3 + 2];
            sum += softplusf(map_class[rn * 4096 + hn * 64 + wn]);
        }
        const float ach = anchor_center[hw];
        const float acw = anchor_center[4096 + hw];
        const float ah = anchor_box[r * 2 + 0];
        const float aw = anchor_box[r * 2 + 1];
        const int g = gt_idx[t];
        const float g0 = gt_boxes[g * 4 + 0], g1 = gt_boxes[g * 4 + 1];
        const float g2 = gt_boxes[g * 4 + 2], g3 = gt_boxes[g * 4 + 3];
        float tgt[4] = { (g0 - ach) / ah, (g1 - acw) / aw, log10f(g2 / ah), log10f(g3 / aw) };
#pragma unroll
        for (int j = 0; j < 4; ++j) {
            float d = map_box[(r * 4 + j) * 4096 + hw] - tgt[j];
            float a = fabsf(d);
            sum += (a < 1.0f) ? 0.5f * d * d : a - 0.5f;
        }
        const int off = (r << 2) * 4096 + hw;
        const float c0 = map_coef[off];
        const float c1 = map_coef[off + 4096];
        const float c2 = map_coef[off + 8192];
        const float c3 = map_coef[off + 12288];
        const float dotT = fmaf(c3, sT[g * 4 + 3], fmaf(c2, sT[g * 4 + 2],
                           fmaf(c1, sT[g * 4 + 1], c0 * sT[g * 4 + 0])));
        contrib = sum + (16.f * SP[t] - dotT) * INV_TOTAL;
    }
    contrib = wave_sum(contrib);
    if (lane == 0) smem[wave] = contrib;
    __syncthreads();
    if (t == 0)
        out[0] = smem[0] + smem[1] + smem[2] + smem[3];
}

extern "C" void kernel_launch(void* const* d_in, const int* in_sizes, int n_in,
                              void* d_out, int out_size, void* d_ws, size_t ws_size,
                              hipStream_t stream) {
    const float* proto         = (const float*)d_in[0];
    const float* map_class     = (const float*)d_in[1];
    const float* map_box       = (const float*)d_in[2];
    const float* map_coef      = (const float*)d_in[3];
    const float* anchor_center = (const float*)d_in[4];
    const float* anchor_box    = (const float*)d_in[5];
    const float* gt_boxes      = (const float*)d_in[6];
    const float* gt_masks      = (const float*)d_in[7];
    const int*   pos_idx       = (const int*)d_in[8];
    const int*   gt_idx        = (const int*)d_in[9];
    const int*   neg_idx       = (const int*)d_in[10];

    float* Tpart = (float*)d_ws;          // 2048 floats
    float* SP    = Tpart + 2048;          // 256 floats
    float* out   = (float*)d_out;

    k_workers<<<768, 256, 0, stream>>>(proto, map_coef, gt_masks, pos_idx, Tpart, SP);
    k_final<<<1, 256, 0, stream>>>(map_class, map_box, map_coef, anchor_center,
                                   anchor_box, gt_boxes, pos_idx, gt_idx, neg_idx,
                                   Tpart, SP, out);
}